// Round 15
// baseline (208.291 us; speedup 1.0000x reference)
//
#include <hip/hip_runtime.h>
#include <math.h>

#define F4(p)  (*reinterpret_cast<float4*>(p))
#define CF4(p) (*reinterpret_cast<const float4*>(p))

#define NCHUNK 16
#define TROWS  12

// ============ shared 64x64-tile GEMM core (256 threads) ============
__device__ __forceinline__ void gemm_core(
    const float* __restrict__ Asrc, const float* __restrict__ inbias,
    const float* __restrict__ til,
    int NS, int srcld, int kc, int k0,
    const float* __restrict__ W, int ldw, int n0,
    const float* __restrict__ obias, float* __restrict__ Pout, int ldo)
{
    __shared__ float As[16*64], Ws[16*64];
    const int t = threadIdx.x;
    const int tx = t & 15, ty = t >> 4;
    const int row = t >> 2, kq = (t & 3) * 4;
    const int wrow = t >> 4, wcol = (t & 15) * 4;
    float acc[4][4] = {};
    for (int kk = 0; kk < kc; kk += 16) {
        const int kg = k0 + kk + kq;
        float4 av;
        if (til && kg >= 256) {
            av = CF4(&til[row*256 + (kg - 256)]);
        } else {
            av = {0.f, 0.f, 0.f, 0.f};
            if (inbias) av = CF4(&inbias[kg]);
            for (int s = 0; s < NS; ++s) {
                float4 v = CF4(&Asrc[(size_t)(s*64 + row)*srcld + kg]);
                av.x += v.x; av.y += v.y; av.z += v.z; av.w += v.w;
            }
        }
        As[(kq+0)*64+row] = av.x; As[(kq+1)*64+row] = av.y;
        As[(kq+2)*64+row] = av.z; As[(kq+3)*64+row] = av.w;
        F4(&Ws[wrow*64 + wcol]) = CF4(&W[(size_t)(k0 + kk + wrow)*ldw + n0 + wcol]);
        __syncthreads();
        #pragma unroll
        for (int k = 0; k < 16; ++k) {
            float4 a4 = CF4(&As[k*64 + ty*4]);
            float4 w4 = CF4(&Ws[k*64 + tx*4]);
            float a[4] = {a4.x, a4.y, a4.z, a4.w};
            float w[4] = {w4.x, w4.y, w4.z, w4.w};
            #pragma unroll
            for (int i = 0; i < 4; ++i)
                #pragma unroll
                for (int j = 0; j < 4; ++j)
                    acc[i][j] += a[i] * w[j];
        }
        __syncthreads();
    }
    #pragma unroll
    for (int i = 0; i < 4; ++i) {
        float4 o = {acc[i][0], acc[i][1], acc[i][2], acc[i][3]};
        if (obias) {
            float4 ob = CF4(&obias[n0 + tx*4]);
            o.x += ob.x; o.y += ob.y; o.z += ob.z; o.w += ob.w;
        }
        F4(&Pout[(size_t)(ty*4 + i)*ldo + n0 + tx*4]) = o;
    }
}

// ============ q-chain as split-K GEMMs ============
__global__ __launch_bounds__(256) void k_q1(
    const float* __restrict__ state, const float* __restrict__ W_state,
    float* __restrict__ P1)
{
    const int nt = blockIdx.x, ks = blockIdx.y;     // 4 x 8
    gemm_core(state, nullptr, nullptr, 1, 512, 64, ks*64,
              W_state, 256, nt*64, nullptr, P1 + (size_t)ks*64*256, 256);
}

__global__ __launch_bounds__(256) void k_q2(
    const float* __restrict__ P1, const float* __restrict__ b_state,
    const float* __restrict__ til, const float* __restrict__ Wcq1,
    float* __restrict__ P2)
{
    const int nt = blockIdx.x, ks = blockIdx.y;     // 8 x 8
    gemm_core(P1, b_state, til, 8, 256, 64, ks*64,
              Wcq1, 512, nt*64, nullptr, P2 + (size_t)ks*64*512, 512);
}

__global__ __launch_bounds__(256) void k_q3(
    const float* __restrict__ P2, const float* __restrict__ bcq1,
    const float* __restrict__ Wcq2, float* __restrict__ P3)
{
    const int nt = blockIdx.x, ks = blockIdx.y;     // 8 x 8
    gemm_core(P2, bcq1, nullptr, 8, 512, 64, ks*64,
              Wcq2, 512, nt*64, nullptr, P3 + (size_t)ks*64*512, 512);
}

__global__ __launch_bounds__(256) void k_qh(
    const float* __restrict__ P3, const float* __restrict__ bcq2,
    const float* __restrict__ Wq, float* __restrict__ P4)
{
    const int nt = blockIdx.x, ks = blockIdx.y;     // 64 x 4
    gemm_core(P3, bcq2, nullptr, 8, 512, 128, ks*128,
              Wq, 4096, nt*64, nullptr, P4 + (size_t)ks*64*4096, 4096);
}

// ============ k_qsum: qh[b] = bq + sum4 P4 ============
__global__ __launch_bounds__(256) void k_qsum(
    const float* __restrict__ P4, const float* __restrict__ bq,
    float* __restrict__ qh)
{
    const int b = blockIdx.x, t = threadIdx.x;
    #pragma unroll
    for (int j = 0; j < 4; ++j) {
        int f = t + j*256;
        float4 v = CF4(&bq[f*4]);
        #pragma unroll
        for (int s = 0; s < 4; ++s) {
            float4 u = CF4(&P4[(size_t)(s*64 + b)*4096 + f*4]);
            v.x += u.x; v.y += u.y; v.z += u.z; v.w += u.w;
        }
        F4(&qh[(size_t)b*4096 + f*4]) = v;
    }
}

// ============ k_fa: flash attention, register-staged LDS tile pipeline ============
__global__ __launch_bounds__(256, 2) void k_fa(
    const float* __restrict__ keys, const float* __restrict__ rpe,
    const float* __restrict__ qh, const float* __restrict__ vals,
    const int* __restrict__ step,
    float* __restrict__ Facc, float* __restrict__ Fms)
{
    __shared__ __align__(16) float s_kt[2][TROWS*512];  // 48KB tiles
    __shared__ float s_sc[72*8];
    __shared__ float s_rpe[64];
    __shared__ float red[256];
    __shared__ float s_m[8];
    const int b = blockIdx.y, lc = blockIdx.x;
    const int sb = step[b];
    const int l0 = (lc * sb) / NCHUNK;
    const int l1 = ((lc + 1) * sb) / NCHUNK;
    const int nl = l1 - l0;                       // <= 64
    const int t = threadIdx.x;
    float* facc_out = Facc + ((size_t)(lc*64) + b)*4096;
    if (nl <= 0) {
        float4 z = {0.f, 0.f, 0.f, 0.f};
        for (int i = t; i < 1024; i += 256) F4(&facc_out[i*4]) = z;
        if (t < 8) {
            size_t o = ((size_t)(lc*64 + b)*8 + t)*2;
            Fms[o] = -1e30f; Fms[o+1] = 0.f;
        }
        return;
    }
    const int ntile = (nl + TROWS - 1) / TROWS;
    const float inv_sqrtK = 0.04419417382415922f;
    const int lane = t & 63, w = t >> 6;

    // ---- staging helpers (6 independent float4 loads per thread per tile) ----
    float4 sreg[6];
    const int sf_r[6]  = { (0*256) >> 7, (1*256) >> 7, 0,0,0,0 };  // placeholder (computed inline)
    (void)sf_r;
    auto stage_load_k = [&](int tile) {
        const int base = tile * TROWS;
        #pragma unroll
        for (int s = 0; s < 6; ++s) {
            int f = s*256 + t;
            int r = f >> 7, c4 = f & 127;
            int g = min(base + r, nl - 1);
            sreg[s] = CF4(&keys[((size_t)(l0 + g)*64 + b)*512 + c4*4]);
        }
    };
    auto stage_load_v = [&](int tile) {
        const int base = tile * TROWS;
        #pragma unroll
        for (int s = 0; s < 6; ++s) {
            int f = s*256 + t;
            int r = f >> 7, c4 = f & 127;
            int g = min(base + r, nl - 1);
            sreg[s] = CF4(&vals[((size_t)(l0 + g)*64 + b)*512 + c4*4]);
        }
    };
    auto stage_write = [&](int buf) {
        #pragma unroll
        for (int s = 0; s < 6; ++s) {
            int f = s*256 + t;
            F4(&s_kt[buf][f*4]) = sreg[s];
        }
    };

    // ---- prologue: tile0 keys + rpe + q fragments ----
    stage_load_k(0);
    if (t < nl) s_rpe[t] = rpe[(l0 + t)*64 + b] * inv_sqrtK;
    float qr[8][8];
    {
        const float* qb = qh + (size_t)b*4096 + lane*8;
        #pragma unroll
        for (int h = 0; h < 8; ++h) {
            float4 x = CF4(&qb[h*512]);
            float4 y = CF4(&qb[h*512 + 4]);
            qr[h][0]=x.x; qr[h][1]=x.y; qr[h][2]=x.z; qr[h][3]=x.w;
            qr[h][4]=y.x; qr[h][5]=y.y; qr[h][6]=y.z; qr[h][7]=y.w;
        }
        #pragma unroll
        for (int h = 0; h < 8; ++h)
            #pragma unroll
            for (int j = 0; j < 8; ++j)
                asm volatile("" : "+v"(qr[h][j]));   // force register residency
    }
    stage_write(0);
    __syncthreads();

    const bool p0 = lane & 1, p1 = lane & 2, p2 = lane & 4;
    // ---- scores over tiles ----
    for (int i = 0; i < ntile; ++i) {
        const int cur = i & 1;
        const bool more = (i + 1 < ntile);
        if (more) stage_load_k(i + 1);            // issue-early
        const int base = i * TROWS;
        #pragma unroll
        for (int r3 = 0; r3 < 3; ++r3) {
            const int r = w + r3*4;               // 0..11
            const int gr = base + r;
            if (gr < nl) {
                float4 kx = CF4(&s_kt[cur][r*512 + lane*8]);
                float4 ky = CF4(&s_kt[cur][r*512 + lane*8 + 4]);
                float kv[8] = {kx.x,kx.y,kx.z,kx.w, ky.x,ky.y,ky.z,ky.w};
                float pr[8] = {};
                #pragma unroll
                for (int h = 0; h < 8; ++h)
                    #pragma unroll
                    for (int j = 0; j < 8; ++j)
                        pr[h] += kv[j] * qr[h][j];
                float w4[4], x2[2], y;
                #pragma unroll
                for (int q = 0; q < 4; ++q) {
                    float keep = p0 ? pr[2*q+1] : pr[2*q];
                    float send = p0 ? pr[2*q]   : pr[2*q+1];
                    w4[q] = keep + __shfl_xor(send, 1);
                }
                #pragma unroll
                for (int q = 0; q < 2; ++q) {
                    float keep = p1 ? w4[2*q+1] : w4[2*q];
                    float send = p1 ? w4[2*q]   : w4[2*q+1];
                    x2[q] = keep + __shfl_xor(send, 2);
                }
                {
                    float keep = p2 ? x2[1] : x2[0];
                    float send = p2 ? x2[0] : x2[1];
                    y = keep + __shfl_xor(send, 4);
                }
                y += __shfl_xor(y, 8);
                y += __shfl_xor(y, 16);
                y += __shfl_xor(y, 32);
                if (lane < 8) s_sc[gr*8 + lane] = y * s_rpe[gr];
            }
        }
        if (more) stage_write(cur ^ 1);           // write-late
        __syncthreads();
    }

    // ---- issue vals tile0 loads early, then softmax stats ----
    stage_load_v(0);
    const int h = t & 7, g = t >> 3;
    float m = -1e30f;
    for (int l = g; l < nl; l += 32) m = fmaxf(m, s_sc[l*8 + h]);
    red[g*8 + h] = m;
    __syncthreads();
    #pragma unroll
    for (int s = 16; s; s >>= 1) {
        if (g < s) red[g*8+h] = fmaxf(red[g*8+h], red[(g+s)*8+h]);
        __syncthreads();
    }
    if (t < 8) s_m[t] = red[t];
    __syncthreads();
    float mh = s_m[h], s_acc = 0.f;
    for (int l = g; l < nl; l += 32) {
        float e = __expf(s_sc[l*8 + h] - mh);
        s_sc[l*8 + h] = e;
        s_acc += e;
    }
    for (int l = nl + g; l < ntile*TROWS; l += 32) s_sc[l*8 + h] = 0.f;
    red[g*8 + h] = s_acc;
    __syncthreads();
    #pragma unroll
    for (int s = 16; s; s >>= 1) {
        if (g < s) red[g*8+h] += red[(g+s)*8+h];
        __syncthreads();
    }
    if (t < 8) {
        size_t o = ((size_t)(lc*64 + b)*8 + t)*2;
        Fms[o] = s_m[t]; Fms[o+1] = red[t];
    }
    stage_write(0);
    __syncthreads();

    // ---- PV over tiles ----
    const int par = t >> 7, c = t & 127;
    float4 acc[8] = {};
    for (int i = 0; i < ntile; ++i) {
        const int cur = i & 1;
        const bool more = (i + 1 < ntile);
        if (more) stage_load_v(i + 1);            // issue-early
        const int base = i * TROWS;
        #pragma unroll
        for (int j = 0; j < 6; ++j) {
            const int r = par + j*2;              // 0..11
            const int gr = base + r;
            float4 v = CF4(&s_kt[cur][r*512 + c*4]);
            float4 pa = CF4(&s_sc[gr*8]);
            float4 pb = CF4(&s_sc[gr*8 + 4]);
            acc[0].x += pa.x*v.x; acc[0].y += pa.x*v.y; acc[0].z += pa.x*v.z; acc[0].w += pa.x*v.w;
            acc[1].x += pa.y*v.x; acc[1].y += pa.y*v.y; acc[1].z += pa.y*v.z; acc[1].w += pa.y*v.w;
            acc[2].x += pa.z*v.x; acc[2].y += pa.z*v.y; acc[2].z += pa.z*v.z; acc[2].w += pa.z*v.w;
            acc[3].x += pa.w*v.x; acc[3].y += pa.w*v.y; acc[3].z += pa.w*v.z; acc[3].w += pa.w*v.w;
            acc[4].x += pb.x*v.x; acc[4].y += pb.x*v.y; acc[4].z += pb.x*v.z; acc[4].w += pb.x*v.w;
            acc[5].x += pb.y*v.x; acc[5].y += pb.y*v.y; acc[5].z += pb.y*v.z; acc[5].w += pb.y*v.w;
            acc[6].x += pb.z*v.x; acc[6].y += pb.z*v.y; acc[6].z += pb.z*v.z; acc[6].w += pb.z*v.w;
            acc[7].x += pb.w*v.x; acc[7].y += pb.w*v.y; acc[7].z += pb.w*v.z; acc[7].w += pb.w*v.w;
        }
        if (more) stage_write(cur ^ 1);           // write-late
        __syncthreads();
    }

    // ---- parity combine (reuse s_kt[0]) and write ----
    float* s_cmb = &s_kt[0][0];
    if (par == 1) {
        #pragma unroll
        for (int hh = 0; hh < 8; ++hh)
            F4(&s_cmb[(c*8 + hh)*4]) = acc[hh];
    }
    __syncthreads();
    if (par == 0) {
        #pragma unroll
        for (int hh = 0; hh < 8; ++hh) {
            float4 o = CF4(&s_cmb[(c*8 + hh)*4]);
            o.x += acc[hh].x; o.y += acc[hh].y; o.z += acc[hh].z; o.w += acc[hh].w;
            F4(&facc_out[hh*512 + c*4]) = o;
        }
    }
}

// ============ k_comb: flash combine -> res[64][4096] ============
__global__ __launch_bounds__(256) void k_comb(
    const float* __restrict__ Facc, const float* __restrict__ Fms,
    float* __restrict__ res)
{
    __shared__ float wgt[NCHUNK*8];
    const int b = blockIdx.x, t = threadIdx.x;
    if (t < 8) {
        float mm[NCHUNK], ss[NCHUNK], e[NCHUNK];
        float M = -1e30f;
        #pragma unroll
        for (int i = 0; i < NCHUNK; ++i) {
            size_t o = ((size_t)(i*64 + b)*8 + t)*2;
            mm[i] = Fms[o]; ss[i] = Fms[o+1];
            M = fmaxf(M, mm[i]);
        }
        float D = 0.f;
        #pragma unroll
        for (int i = 0; i < NCHUNK; ++i) { e[i] = __expf(mm[i] - M); D += e[i]*ss[i]; }
        float invD = 1.f / D;
        #pragma unroll
        for (int i = 0; i < NCHUNK; ++i) wgt[i*8 + t] = e[i] * invD;
    }
    __syncthreads();
    #pragma unroll
    for (int j = 0; j < 4; ++j) {
        int f = t + j*256;
        int h = f >> 7;
        float4 a = {0.f, 0.f, 0.f, 0.f};
        #pragma unroll
        for (int i = 0; i < NCHUNK; ++i) {
            float wi = wgt[i*8 + h];
            float4 v = CF4(&Facc[((size_t)(i*64) + b)*4096 + f*4]);
            a.x += wi*v.x; a.y += wi*v.y; a.z += wi*v.z; a.w += wi*v.w;
        }
        F4(&res[(size_t)b*4096 + f*4]) = a;
    }
}

// ============ tail GEMMs ============
__global__ __launch_bounds__(256) void k_agg(
    const float* __restrict__ res, const float* __restrict__ Wagg,
    float* __restrict__ P5)
{
    const int nt = blockIdx.x, ks = blockIdx.y;     // 8 x 32
    gemm_core(res, nullptr, nullptr, 1, 4096, 128, ks*128,
              Wagg, 512, nt*64, nullptr, P5 + (size_t)ks*64*512, 512);
}

__global__ __launch_bounds__(256) void k_rkv1(
    const float* __restrict__ P5, const float* __restrict__ bagg,
    const float* __restrict__ Wrk1, const float* __restrict__ Wrv1,
    float* __restrict__ P6)
{
    const int nt = blockIdx.x, ks = blockIdx.y, z = blockIdx.z;  // 8 x 4 x 2
    gemm_core(P5, bagg, nullptr, 32, 512, 128, ks*128,
              z ? Wrv1 : Wrk1, 512, nt*64,
              nullptr, P6 + (size_t)(z*4 + ks)*64*512, 512);
}

__global__ __launch_bounds__(256) void k_rkv2(
    const float* __restrict__ P6,
    const float* __restrict__ brk1, const float* __restrict__ brv1,
    const float* __restrict__ Wrk2, const float* __restrict__ Wrv2,
    const float* __restrict__ brk2, const float* __restrict__ brv2,
    float* __restrict__ out)
{
    const int nt = blockIdx.x, z = blockIdx.z;      // 8 x 1 x 2
    gemm_core(P6 + (size_t)z*4*64*512, z ? brv1 : brk1, nullptr, 4, 512, 512, 0,
              z ? Wrv2 : Wrk2, 512, nt*64,
              z ? brv2 : brk2, out + (size_t)z*64*512, 512);
}

// ============ launch ============
extern "C" void kernel_launch(void* const* d_in, const int* in_sizes, int n_in,
                              void* d_out, int out_size, void* d_ws, size_t ws_size,
                              hipStream_t stream) {
    const float* state   = (const float*)d_in[0];
    const float* til     = (const float*)d_in[1];
    const float* keys    = (const float*)d_in[2];
    const float* vals    = (const float*)d_in[3];
    const float* rpe     = (const float*)d_in[4];
    const int*   step    = (const int*)d_in[5];
    const float* W_state = (const float*)d_in[6];
    const float* b_state = (const float*)d_in[7];
    const float* Wcq1 = (const float*)d_in[8];
    const float* bcq1 = (const float*)d_in[9];
    const float* Wcq2 = (const float*)d_in[10];
    const float* bcq2 = (const float*)d_in[11];
    const float* Wq   = (const float*)d_in[12];
    const float* bq   = (const float*)d_in[13];
    const float* Wagg = (const float*)d_in[14];
    const float* bagg = (const float*)d_in[15];
    const float* Wrk1 = (const float*)d_in[16];
    const float* brk1 = (const float*)d_in[17];
    const float* Wrk2 = (const float*)d_in[18];
    const float* brk2 = (const float*)d_in[19];
    const float* Wrv1 = (const float*)d_in[20];
    const float* brv1 = (const float*)d_in[21];
    const float* Wrv2 = (const float*)d_in[22];
    const float* brv2 = (const float*)d_in[23];
    float* out = (float*)d_out;
    float* ws  = (float*)d_ws;

    float* P1   = ws;              // [8][64][256]   131072  dead after k_q2
    float* P2   = ws + 131072;     // [8][64][512]   262144  dead after k_q3
    float* P3   = ws + 393216;     // [8][64][512]   262144  dead after k_qh
    float* P4   = ws + 655360;     // [4][64][4096]  1048576 dead after k_qsum
    float* qh   = ws + 1703936;    // [64][4096]     262144
    float* Facc = ws + 1966080;    // [16][64][4096] 4194304
    float* Fms  = ws + 6160384;    // 16*64*8*2      16384
    float* res  = ws + 6176768;    // [64][4096]     262144
    float* P5   = ws;              // [32][64][512]  1048576 (reuses P1..P4)
    float* P6   = ws + 1048576;    // [2][4][64][512] 262144 (reuses P4 tail)

    k_q1  <<<dim3(4,8),   256, 0, stream>>>(state, W_state, P1);
    k_q2  <<<dim3(8,8),   256, 0, stream>>>(P1, b_state, til, Wcq1, P2);
    k_q3  <<<dim3(8,8),   256, 0, stream>>>(P2, bcq1, Wcq2, P3);
    k_qh  <<<dim3(64,4),  256, 0, stream>>>(P3, bcq2, Wq, P4);
    k_qsum<<<64, 256, 0, stream>>>(P4, bq, qh);
    k_fa  <<<dim3(NCHUNK,64), 256, 0, stream>>>(keys, rpe, qh, vals, step, Facc, Fms);
    k_comb<<<64, 256, 0, stream>>>(Facc, Fms, res);
    k_agg <<<dim3(8,32),  256, 0, stream>>>(res, Wagg, P5);
    k_rkv1<<<dim3(8,4,2), 256, 0, stream>>>(P5, bagg, Wrk1, Wrv1, P6);
    k_rkv2<<<dim3(8,1,2), 256, 0, stream>>>(P6, brk1, brv1, Wrk2, Wrv2,
                                            brk2, brv2, out);
}

// Round 16
// 161.868 us; speedup vs baseline: 1.2868x; 1.2868x over previous
//
#include <hip/hip_runtime.h>
#include <math.h>

#define F4(p)  (*reinterpret_cast<float4*>(p))
#define CF4(p) (*reinterpret_cast<const float4*>(p))

#define NCHUNK 16

// ============ shared 64x64-tile GEMM core (256 threads) ============
__device__ __forceinline__ void gemm_core(
    const float* __restrict__ Asrc, const float* __restrict__ inbias,
    const float* __restrict__ til,
    int NS, int srcld, int kc, int k0,
    const float* __restrict__ W, int ldw, int n0,
    const float* __restrict__ obias, float* __restrict__ Pout, int ldo)
{
    __shared__ float As[16*64], Ws[16*64];
    const int t = threadIdx.x;
    const int tx = t & 15, ty = t >> 4;
    const int row = t >> 2, kq = (t & 3) * 4;
    const int wrow = t >> 4, wcol = (t & 15) * 4;
    float acc[4][4] = {};
    for (int kk = 0; kk < kc; kk += 16) {
        const int kg = k0 + kk + kq;
        float4 av;
        if (til && kg >= 256) {
            av = CF4(&til[row*256 + (kg - 256)]);
        } else {
            av = {0.f, 0.f, 0.f, 0.f};
            if (inbias) av = CF4(&inbias[kg]);
            for (int s = 0; s < NS; ++s) {
                float4 v = CF4(&Asrc[(size_t)(s*64 + row)*srcld + kg]);
                av.x += v.x; av.y += v.y; av.z += v.z; av.w += v.w;
            }
        }
        As[(kq+0)*64+row] = av.x; As[(kq+1)*64+row] = av.y;
        As[(kq+2)*64+row] = av.z; As[(kq+3)*64+row] = av.w;
        F4(&Ws[wrow*64 + wcol]) = CF4(&W[(size_t)(k0 + kk + wrow)*ldw + n0 + wcol]);
        __syncthreads();
        #pragma unroll
        for (int k = 0; k < 16; ++k) {
            float4 a4 = CF4(&As[k*64 + ty*4]);
            float4 w4 = CF4(&Ws[k*64 + tx*4]);
            float a[4] = {a4.x, a4.y, a4.z, a4.w};
            float w[4] = {w4.x, w4.y, w4.z, w4.w};
            #pragma unroll
            for (int i = 0; i < 4; ++i)
                #pragma unroll
                for (int j = 0; j < 4; ++j)
                    acc[i][j] += a[i] * w[j];
        }
        __syncthreads();
    }
    #pragma unroll
    for (int i = 0; i < 4; ++i) {
        float4 o = {acc[i][0], acc[i][1], acc[i][2], acc[i][3]};
        if (obias) {
            float4 ob = CF4(&obias[n0 + tx*4]);
            o.x += ob.x; o.y += ob.y; o.z += ob.z; o.w += ob.w;
        }
        F4(&Pout[(size_t)(ty*4 + i)*ldo + n0 + tx*4]) = o;
    }
}

// ============ q-chain as split-K GEMMs ============
__global__ __launch_bounds__(256) void k_q1(
    const float* __restrict__ state, const float* __restrict__ W_state,
    float* __restrict__ P1)
{
    const int nt = blockIdx.x, ks = blockIdx.y;     // 4 x 8
    gemm_core(state, nullptr, nullptr, 1, 512, 64, ks*64,
              W_state, 256, nt*64, nullptr, P1 + (size_t)ks*64*256, 256);
}

__global__ __launch_bounds__(256) void k_q2(
    const float* __restrict__ P1, const float* __restrict__ b_state,
    const float* __restrict__ til, const float* __restrict__ Wcq1,
    float* __restrict__ P2)
{
    const int nt = blockIdx.x, ks = blockIdx.y;     // 8 x 8
    gemm_core(P1, b_state, til, 8, 256, 64, ks*64,
              Wcq1, 512, nt*64, nullptr, P2 + (size_t)ks*64*512, 512);
}

__global__ __launch_bounds__(256) void k_q3(
    const float* __restrict__ P2, const float* __restrict__ bcq1,
    const float* __restrict__ Wcq2, float* __restrict__ P3)
{
    const int nt = blockIdx.x, ks = blockIdx.y;     // 8 x 8
    gemm_core(P2, bcq1, nullptr, 8, 512, 64, ks*64,
              Wcq2, 512, nt*64, nullptr, P3 + (size_t)ks*64*512, 512);
}

__global__ __launch_bounds__(256) void k_qh(
    const float* __restrict__ P3, const float* __restrict__ bcq2,
    const float* __restrict__ Wq, float* __restrict__ P4)
{
    const int nt = blockIdx.x, ks = blockIdx.y;     // 64 x 4
    gemm_core(P3, bcq2, nullptr, 8, 512, 128, ks*128,
              Wq, 4096, nt*64, nullptr, P4 + (size_t)ks*64*4096, 4096);
}

// ============ k_fa: fused online-softmax flash attention ============
// One pass over rows: per row load keys+vals together, online (m, s[8], acc).
// Wave-autonomous main loop (no barriers); block-end wave combine in LDS.
__global__ __launch_bounds__(256, 2) void k_fa(
    const float* __restrict__ keys, const float* __restrict__ rpe,
    const float* __restrict__ P4, const float* __restrict__ bq,
    const float* __restrict__ vals, const int* __restrict__ step,
    float* __restrict__ Facc, float* __restrict__ Fms)
{
    __shared__ __align__(16) float s_q[4096];        // q_eff; reused as wave0 slot
    __shared__ __align__(16) float s_acc3[3*4096];   // waves 1..3 slots
    __shared__ float s_rpe[64];
    __shared__ float s_ms[4*9];                      // per wave: m, s[8]
    const int b = blockIdx.y, lc = blockIdx.x;
    const int sb = step[b];
    const int l0 = (lc * sb) / NCHUNK;
    const int l1 = ((lc + 1) * sb) / NCHUNK;
    const int nl = l1 - l0;                          // <= 64
    const int t = threadIdx.x;
    float* facc_out = Facc + ((size_t)(lc*64) + b)*4096;
    if (nl <= 0) {
        float4 z = {0.f, 0.f, 0.f, 0.f};
        for (int i = t; i < 1024; i += 256) F4(&facc_out[i*4]) = z;
        if (t < 8) {
            size_t o = ((size_t)(lc*64 + b)*8 + t)*2;
            Fms[o] = -1e30f; Fms[o+1] = 0.f;
        }
        return;
    }
    const float inv_sqrtK = 0.04419417382415922f;
    // stage q_eff = bq + sum4 P4 (merged k_qsum) and rpe
    for (int i = t; i < 1024; i += 256) {
        float4 v = CF4(&bq[i*4]);
        #pragma unroll
        for (int s = 0; s < 4; ++s) {
            float4 u = CF4(&P4[(size_t)(s*64 + b)*4096 + i*4]);
            v.x += u.x; v.y += u.y; v.z += u.z; v.w += u.w;
        }
        F4(&s_q[i*4]) = v;
    }
    if (t < nl) s_rpe[t] = rpe[(l0 + t)*64 + b] * inv_sqrtK;
    __syncthreads();

    const int lane = t & 63, w = t >> 6;
    float qr[8][8];
    #pragma unroll
    for (int h = 0; h < 8; ++h) {
        float4 x = CF4(&s_q[h*512 + lane*8]);
        float4 y = CF4(&s_q[h*512 + lane*8 + 4]);
        qr[h][0]=x.x; qr[h][1]=x.y; qr[h][2]=x.z; qr[h][3]=x.w;
        qr[h][4]=y.x; qr[h][5]=y.y; qr[h][6]=y.z; qr[h][7]=y.w;
    }
    const bool p0 = lane & 1, p1 = lane & 2, p2 = lane & 4;

    float m_run = -1e30f;
    float srun[8] = {0.f,0.f,0.f,0.f,0.f,0.f,0.f,0.f};
    float4 accA[8] = {}, accB[8] = {};

    for (int r = w; r < nl; r += 4) {
        const size_t rowoff = ((size_t)(l0 + r)*64 + b)*512 + lane*8;
        const float* kp = keys + rowoff;
        const float* vp = vals + rowoff;
        float4 kx = CF4(kp), ky = CF4(kp + 4);
        float4 vx = CF4(vp), vy = CF4(vp + 4);
        // ---- score ----
        float kv[8] = {kx.x,kx.y,kx.z,kx.w, ky.x,ky.y,ky.z,ky.w};
        float pr[8] = {};
        #pragma unroll
        for (int h = 0; h < 8; ++h)
            #pragma unroll
            for (int j = 0; j < 8; ++j)
                pr[h] += kv[j] * qr[h][j];
        float w4[4], x2[2], y;
        #pragma unroll
        for (int q = 0; q < 4; ++q) {
            float keep = p0 ? pr[2*q+1] : pr[2*q];
            float send = p0 ? pr[2*q]   : pr[2*q+1];
            w4[q] = keep + __shfl_xor(send, 1);
        }
        #pragma unroll
        for (int q = 0; q < 2; ++q) {
            float keep = p1 ? w4[2*q+1] : w4[2*q];
            float send = p1 ? w4[2*q]   : w4[2*q+1];
            x2[q] = keep + __shfl_xor(send, 2);
        }
        {
            float keep = p2 ? x2[1] : x2[0];
            float send = p2 ? x2[0] : x2[1];
            y = keep + __shfl_xor(send, 4);
        }
        y += __shfl_xor(y, 8);
        y += __shfl_xor(y, 16);
        y += __shfl_xor(y, 32);
        y *= s_rpe[r];
        // gather all 8 head scores (uniform per 8-lane group -> uniform wave)
        float p[8];
        #pragma unroll
        for (int hh = 0; hh < 8; ++hh)
            p[hh] = __shfl(y, (lane & 56) | hh);
        float pmax = fmaxf(fmaxf(fmaxf(p[0],p[1]), fmaxf(p[2],p[3])),
                           fmaxf(fmaxf(p[4],p[5]), fmaxf(p[6],p[7])));
        // defer-max: only rescale when the running anchor is exceeded by >8
        if (pmax > m_run + 8.f) {
            float scale = __expf(m_run - pmax);
            #pragma unroll
            for (int hh = 0; hh < 8; ++hh) {
                srun[hh] *= scale;
                accA[hh].x *= scale; accA[hh].y *= scale; accA[hh].z *= scale; accA[hh].w *= scale;
                accB[hh].x *= scale; accB[hh].y *= scale; accB[hh].z *= scale; accB[hh].w *= scale;
            }
            m_run = pmax;
        }
        float e[8];
        #pragma unroll
        for (int hh = 0; hh < 8; ++hh) e[hh] = __expf(p[hh] - m_run);
        #pragma unroll
        for (int hh = 0; hh < 8; ++hh) {
            srun[hh] += e[hh];
            accA[hh].x += e[hh]*vx.x; accA[hh].y += e[hh]*vx.y;
            accA[hh].z += e[hh]*vx.z; accA[hh].w += e[hh]*vx.w;
            accB[hh].x += e[hh]*vy.x; accB[hh].y += e[hh]*vy.y;
            accB[hh].z += e[hh]*vy.z; accB[hh].w += e[hh]*vy.w;
        }
    }
    __syncthreads();    // all waves done (incl. any compiler re-reads of s_q)
    {
        float* slot = (w == 0) ? s_q : (s_acc3 + (w-1)*4096);
        #pragma unroll
        for (int hh = 0; hh < 8; ++hh) {
            F4(&slot[hh*512 + lane*8])     = accA[hh];
            F4(&slot[hh*512 + lane*8 + 4]) = accB[hh];
        }
        if (lane == 0) s_ms[w*9] = m_run;
        if (lane < 8)  s_ms[w*9 + 1 + lane] = srun[lane];
    }
    __syncthreads();
    // ---- combine 4 wave partials -> Facc (anchored at block max M) ----
    const float m0 = s_ms[0], m1 = s_ms[9], m2 = s_ms[18], m3 = s_ms[27];
    const float M  = fmaxf(fmaxf(m0, m1), fmaxf(m2, m3));
    const float e0 = __expf(m0 - M), e1 = __expf(m1 - M);
    const float e2 = __expf(m2 - M), e3 = __expf(m3 - M);
    #pragma unroll
    for (int j = 0; j < 4; ++j) {
        int f = t + j*256;
        float4 a0 = CF4(&s_q[f*4]);
        float4 a1 = CF4(&s_acc3[f*4]);
        float4 a2 = CF4(&s_acc3[4096 + f*4]);
        float4 a3 = CF4(&s_acc3[8192 + f*4]);
        float4 o;
        o.x = e0*a0.x + e1*a1.x + e2*a2.x + e3*a3.x;
        o.y = e0*a0.y + e1*a1.y + e2*a2.y + e3*a3.y;
        o.z = e0*a0.z + e1*a1.z + e2*a2.z + e3*a3.z;
        o.w = e0*a0.w + e1*a1.w + e2*a2.w + e3*a3.w;
        F4(&facc_out[f*4]) = o;
    }
    if (t < 8) {
        float stot = e0*s_ms[1+t] + e1*s_ms[10+t] + e2*s_ms[19+t] + e3*s_ms[28+t];
        size_t o = ((size_t)(lc*64 + b)*8 + t)*2;
        Fms[o] = M; Fms[o+1] = stot;
    }
}

// ============ k_comb: flash combine -> res[64][4096] ============
__global__ __launch_bounds__(256) void k_comb(
    const float* __restrict__ Facc, const float* __restrict__ Fms,
    float* __restrict__ res)
{
    __shared__ float wgt[NCHUNK*8];
    const int b = blockIdx.x, t = threadIdx.x;
    if (t < 8) {
        float mm[NCHUNK], ss[NCHUNK], e[NCHUNK];
        float M = -1e30f;
        #pragma unroll
        for (int i = 0; i < NCHUNK; ++i) {
            size_t o = ((size_t)(i*64 + b)*8 + t)*2;
            mm[i] = Fms[o]; ss[i] = Fms[o+1];
            M = fmaxf(M, mm[i]);
        }
        float D = 0.f;
        #pragma unroll
        for (int i = 0; i < NCHUNK; ++i) { e[i] = __expf(mm[i] - M); D += e[i]*ss[i]; }
        float invD = 1.f / D;
        #pragma unroll
        for (int i = 0; i < NCHUNK; ++i) wgt[i*8 + t] = e[i] * invD;
    }
    __syncthreads();
    #pragma unroll
    for (int j = 0; j < 4; ++j) {
        int f = t + j*256;
        int h = f >> 7;
        float4 a = {0.f, 0.f, 0.f, 0.f};
        #pragma unroll
        for (int i = 0; i < NCHUNK; ++i) {
            float wi = wgt[i*8 + h];
            float4 v = CF4(&Facc[((size_t)(i*64) + b)*4096 + f*4]);
            a.x += wi*v.x; a.y += wi*v.y; a.z += wi*v.z; a.w += wi*v.w;
        }
        F4(&res[(size_t)b*4096 + f*4]) = a;
    }
}

// ============ tail GEMMs ============
__global__ __launch_bounds__(256) void k_agg(
    const float* __restrict__ res, const float* __restrict__ Wagg,
    float* __restrict__ P5)
{
    const int nt = blockIdx.x, ks = blockIdx.y;     // 8 x 32
    gemm_core(res, nullptr, nullptr, 1, 4096, 128, ks*128,
              Wagg, 512, nt*64, nullptr, P5 + (size_t)ks*64*512, 512);
}

__global__ __launch_bounds__(256) void k_rkv1(
    const float* __restrict__ P5, const float* __restrict__ bagg,
    const float* __restrict__ Wrk1, const float* __restrict__ Wrv1,
    float* __restrict__ P6)
{
    const int nt = blockIdx.x, ks = blockIdx.y, z = blockIdx.z;  // 8 x 4 x 2
    gemm_core(P5, bagg, nullptr, 32, 512, 128, ks*128,
              z ? Wrv1 : Wrk1, 512, nt*64,
              nullptr, P6 + (size_t)(z*4 + ks)*64*512, 512);
}

__global__ __launch_bounds__(256) void k_rkv2(
    const float* __restrict__ P6,
    const float* __restrict__ brk1, const float* __restrict__ brv1,
    const float* __restrict__ Wrk2, const float* __restrict__ Wrv2,
    const float* __restrict__ brk2, const float* __restrict__ brv2,
    float* __restrict__ out)
{
    const int nt = blockIdx.x, z = blockIdx.z;      // 8 x 1 x 2
    gemm_core(P6 + (size_t)z*4*64*512, z ? brv1 : brk1, nullptr, 4, 512, 512, 0,
              z ? Wrv2 : Wrk2, 512, nt*64,
              z ? brv2 : brk2, out + (size_t)z*64*512, 512);
}

// ============ launch ============
extern "C" void kernel_launch(void* const* d_in, const int* in_sizes, int n_in,
                              void* d_out, int out_size, void* d_ws, size_t ws_size,
                              hipStream_t stream) {
    const float* state   = (const float*)d_in[0];
    const float* til     = (const float*)d_in[1];
    const float* keys    = (const float*)d_in[2];
    const float* vals    = (const float*)d_in[3];
    const float* rpe     = (const float*)d_in[4];
    const int*   step    = (const int*)d_in[5];
    const float* W_state = (const float*)d_in[6];
    const float* b_state = (const float*)d_in[7];
    const float* Wcq1 = (const float*)d_in[8];
    const float* bcq1 = (const float*)d_in[9];
    const float* Wcq2 = (const float*)d_in[10];
    const float* bcq2 = (const float*)d_in[11];
    const float* Wq   = (const float*)d_in[12];
    const float* bq   = (const float*)d_in[13];
    const float* Wagg = (const float*)d_in[14];
    const float* bagg = (const float*)d_in[15];
    const float* Wrk1 = (const float*)d_in[16];
    const float* brk1 = (const float*)d_in[17];
    const float* Wrk2 = (const float*)d_in[18];
    const float* brk2 = (const float*)d_in[19];
    const float* Wrv1 = (const float*)d_in[20];
    const float* brv1 = (const float*)d_in[21];
    const float* Wrv2 = (const float*)d_in[22];
    const float* brv2 = (const float*)d_in[23];
    float* out = (float*)d_out;
    float* ws  = (float*)d_ws;

    float* P1   = ws;              // [8][64][256]   131072  dead after k_q2
    float* P2   = ws + 131072;     // [8][64][512]   262144  dead after k_q3
    float* P3   = ws + 393216;     // [8][64][512]   262144  dead after k_qh
    float* P4   = ws + 655360;     // [4][64][4096]  1048576 dead after k_fa
    float* Facc = ws + 1966080;    // [16][64][4096] 4194304
    float* Fms  = ws + 6160384;    // 16*64*8*2      16384
    float* res  = ws + 6176768;    // [64][4096]     262144
    float* P5   = ws;              // [32][64][512]  1048576 (reuses P1..P3)
    float* P6   = ws + 1048576;    // [2][4][64][512] 262144 (reuses P4 head)

    k_q1  <<<dim3(4,8),   256, 0, stream>>>(state, W_state, P1);
    k_q2  <<<dim3(8,8),   256, 0, stream>>>(P1, b_state, til, Wcq1, P2);
    k_q3  <<<dim3(8,8),   256, 0, stream>>>(P2, bcq1, Wcq2, P3);
    k_qh  <<<dim3(64,4),  256, 0, stream>>>(P3, bcq2, Wq, P4);
    k_fa  <<<dim3(NCHUNK,64), 256, 0, stream>>>(keys, rpe, P4, bq, vals, step, Facc, Fms);
    k_comb<<<64, 256, 0, stream>>>(Facc, Fms, res);
    k_agg <<<dim3(8,32),  256, 0, stream>>>(res, Wagg, P5);
    k_rkv1<<<dim3(8,4,2), 256, 0, stream>>>(P5, bagg, Wrk1, Wrv1, P6);
    k_rkv2<<<dim3(8,1,2), 256, 0, stream>>>(P6, brk1, brv1, Wrk2, Wrv2,
                                            brk2, brv2, out);
}